// Round 6
// baseline (237.778 us; speedup 1.0000x reference)
//
#include <hip/hip_runtime.h>

typedef __attribute__((ext_vector_type(8))) short bf16x8;
typedef __attribute__((ext_vector_type(4))) float f32x4;

#define NB    4096
#define NLINK 33
#define NJ    32
#define KTOT  1024
#define CJ    128
#define BM    32

// Pre-converted, fragment-swizzled bf16 W (8.4 MB), rebuilt every call.
// Cell ((j*32 + kt)*128 + c)*4 + q holds bf16x8 of W[j][kt*32 + q*8 + e][c].
// (Layout correctness-verified R2-R5.)
__device__ short g_Wf[NJ * KTOT * CJ];

// round-to-nearest-even f32 -> bf16 (finite inputs)
static __device__ __forceinline__ short f2bf(float f) {
    unsigned u = __builtin_bit_cast(unsigned, f);
    unsigned r = u + 0x7FFFu + ((u >> 16) & 1u);
    return (short)(r >> 16);
}

__global__ __launch_bounds__(256) void conv_w(const float* __restrict__ W) {
    const int gid = blockIdx.x * 256 + threadIdx.x;
    const int q  = gid & 3;
    const int c  = (gid >> 2) & 127;
    const int kt = (gid >> 9) & 31;
    const int j  = gid >> 14;
    const float* src = W + ((size_t)j * KTOT + kt * 32 + q * 8) * CJ + c;
    bf16x8 v;
    #pragma unroll
    for (int e = 0; e < 8; ++e) v[e] = f2bf(src[(size_t)e * CJ]);
    reinterpret_cast<bf16x8*>(g_Wf)[gid] = v;
}

// Single-touch A: stage full K=1024 (4KB/row, one contiguous burst per row,
// each row read exactly once in the whole kernel), then compute from LDS.
// 2 barriers per block total. 2 blocks/CU anti-phase (stage || compute).
__global__ __launch_bounds__(256, 2) void joint_gemm(
    const float* __restrict__ link,
    const float* __restrict__ jf,
    const float* __restrict__ bias,
    const int*   __restrict__ child,
    float* __restrict__ out)
{
    // 32 rows x 128 cells(16B). phys_cell = cell ^ (4*(row&15)).
    // ds_write 2-way (free), ds_read_b128 conflict-free (derivation in journal).
    __shared__ short lA[BM * 1024];   // 64 KB

    const int tid  = threadIdx.x;
    const int lane = tid & 63;
    const int wave = tid >> 6;     // 0..3
    const int wr   = wave >> 1;    // 0..1 : 16-row block
    const int wc   = wave & 1;     // 0..1 : 64-col half
    const int q    = lane >> 4;    // 0..3
    const int r    = lane & 15;    // 0..15

    const int j  = blockIdx.x & 31;   // j-minor: 4 joints/XCD -> 1MB W in XCD L2
    const int mt = blockIdx.x >> 5;
    const int row0 = mt * BM;
    const int cidx = child[j];

    // ---- phase 1: stage A, one 4KB contiguous burst per row ----
    {
        const int srow = tid & 31;     // row
        const int sk   = tid >> 5;     // 0..7
        const float* ab = link + ((size_t)(row0 + srow) * NLINK + cidx) * KTOT;
        short* lrow = lA + srow * 1024;
        const int skey = 4 * (srow & 15);
        #pragma unroll
        for (int i = 0; i < 16; ++i) {
            const int cell = i * 8 + sk;
            const float4 f0 = *reinterpret_cast<const float4*>(ab + cell * 8);
            const float4 f1 = *reinterpret_cast<const float4*>(ab + cell * 8 + 4);
            bf16x8 v;
            v[0] = f2bf(f0.x); v[1] = f2bf(f0.y); v[2] = f2bf(f0.z); v[3] = f2bf(f0.w);
            v[4] = f2bf(f1.x); v[5] = f2bf(f1.y); v[6] = f2bf(f1.z); v[7] = f2bf(f1.w);
            *reinterpret_cast<bf16x8*>(lrow + (cell ^ skey) * 8) = v;
        }
    }
    __syncthreads();

    // ---- phase 2: K loop from LDS (A) + L2 g_Wf (B) ----
    const bf16x8* wb = reinterpret_cast<const bf16x8*>(g_Wf);
    const size_t bb = (size_t)j * 16384 + ((size_t)wc * 64 + r) * 4 + q;

    // early jf/bias issue (overlaps with K loop)
    float bv[4];
    float jv[4][4];
    {
        #pragma unroll
        for (int nb = 0; nb < 4; ++nb) bv[nb] = bias[j * CJ + wc * 64 + nb * 16 + r];
        #pragma unroll
        for (int rr = 0; rr < 4; ++rr) {
            const int bg = row0 + wr * 16 + q * 4 + rr;
            const size_t ob = ((size_t)bg * NJ + j) * CJ + wc * 64;
            #pragma unroll
            for (int nb = 0; nb < 4; ++nb) jv[rr][nb] = jf[ob + nb * 16 + r];
        }
    }

    f32x4 acc[4] = {};
    const short* arow = lA + (wr * 16 + r) * 1024;
    const int rkey = 4 * r;

    #pragma unroll
    for (int ks = 0; ks < 32; ++ks) {
        const bf16x8 af = *reinterpret_cast<const bf16x8*>(arow + ((ks * 4 + q) ^ rkey) * 8);
        const bf16x8 b0 = wb[bb + (size_t)ks * 512];
        const bf16x8 b1 = wb[bb + (size_t)ks * 512 + 64];
        const bf16x8 b2 = wb[bb + (size_t)ks * 512 + 128];
        const bf16x8 b3 = wb[bb + (size_t)ks * 512 + 192];
        acc[0] = __builtin_amdgcn_mfma_f32_16x16x32_bf16(af, b0, acc[0], 0, 0, 0);
        acc[1] = __builtin_amdgcn_mfma_f32_16x16x32_bf16(af, b1, acc[1], 0, 0, 0);
        acc[2] = __builtin_amdgcn_mfma_f32_16x16x32_bf16(af, b2, acc[2], 0, 0, 0);
        acc[3] = __builtin_amdgcn_mfma_f32_16x16x32_bf16(af, b3, acc[3], 0, 0, 0);
    }

    // ---- epilogue ----
    #pragma unroll
    for (int rr = 0; rr < 4; ++rr) {
        const int bg = row0 + wr * 16 + q * 4 + rr;
        const size_t ob = ((size_t)bg * NJ + j) * CJ + wc * 64;
        #pragma unroll
        for (int nb = 0; nb < 4; ++nb)
            out[ob + nb * 16 + r] = acc[nb][rr] + bv[nb] + jv[rr][nb];
    }
}

extern "C" void kernel_launch(void* const* d_in, const int* in_sizes, int n_in,
                              void* d_out, int out_size, void* d_ws, size_t ws_size,
                              hipStream_t stream) {
    (void)in_sizes; (void)n_in; (void)out_size; (void)d_ws; (void)ws_size;
    const float* link  = (const float*)d_in[0];
    const float* jfeat = (const float*)d_in[1];
    const float* W     = (const float*)d_in[2];
    const float* bias  = (const float*)d_in[3];
    const int*   child = (const int*)d_in[4];
    float* out = (float*)d_out;

    conv_w<<<dim3((NJ * KTOT * CJ / 8) / 256), dim3(256), 0, stream>>>(W);
    joint_gemm<<<dim3(NJ * (NB / BM)), dim3(256), 0, stream>>>(link, jfeat, bias, child, out);
}